// Round 12
// baseline (130.978 us; speedup 1.0000x reference)
//
#include <hip/hip_runtime.h>
#include <math.h>

// B=2, WAY=5, SHOT=5, K=5, Q=30, DIM=64, HW=441
// Single-bf16 MFMA (16x16x32).
//  ip_p: per (e,w): C^T[k=sh*441+h (2208)][cols=(q,h) 448/q], K=d(64)
//  ip_l: per (e,w): C^T[k=sh*64+d' (320)][cols=(q,d) 1920], K=h(448)
// k56 pixel (R12): block = ONE gwave x 4 k-quarter waves (2100 blocks,
// 8400 waves -> ~5 waves/SIMD). No LDS staging, no in-loop barriers:
// each wave streams its 35-kt quarter from L2 with distance-1 prefetch.
// Cross-quarter top5 merge once per block via LDS. R5-R11 were wave-starved
// (3360 waves, ~2/SIMD; 730 cyc/kt vs 220 demand -> VALUBusy stuck ~50%).

typedef __attribute__((ext_vector_type(8))) short bf16x8;
typedef __attribute__((ext_vector_type(4))) float f32x4;

#define MFMA16(a, b, c) __builtin_amdgcn_mfma_f32_16x16x32_bf16((a), (b), (c), 0, 0, 0)

__device__ __forceinline__ unsigned short to_bf16(float v) {
    unsigned int u = __float_as_uint(v);
    unsigned int r = u + 0x7FFFu + ((u >> 16) & 1u);
    return (unsigned short)(r >> 16);
}

// sorted-desc top5 insert via v_med3_f32: 5 VALU ops.
__device__ __forceinline__ void ins5(float m[5], float v) {
    m[4] = __builtin_amdgcn_fmed3f(v, m[4], m[3]);
    m[3] = __builtin_amdgcn_fmed3f(v, m[3], m[2]);
    m[2] = __builtin_amdgcn_fmed3f(v, m[2], m[1]);
    m[1] = __builtin_amdgcn_fmed3f(v, m[1], m[0]);
    m[0] = fmaxf(m[0], v);
}

// ---------------- k1: row norms + row means ----------------
__global__ __launch_bounds__(256) void k1_rownorm(const float* __restrict__ in1,
                                                  const float* __restrict__ in2,
                                                  float* __restrict__ inv_norm,
                                                  float* __restrict__ pool) {
    int wv = threadIdx.x >> 6;
    int lane = threadIdx.x & 63;
    int rid = blockIdx.x * 4 + wv;  // 0..7039
    const float* src = (rid < 3840) ? (in1 + (size_t)rid * 441)
                                    : (in2 + (size_t)(rid - 3840) * 441);
    float s = 0.f, ss = 0.f;
#pragma unroll
    for (int i = 0; i < 7; ++i) {
        int h = lane + i * 64;
        if (h < 441) { float v = src[h]; s += v; ss = fmaf(v, v, ss); }
    }
#pragma unroll
    for (int off = 32; off > 0; off >>= 1) {
        s += __shfl_xor(s, off, 64);
        ss += __shfl_xor(ss, off, 64);
    }
    if (lane == 0) {
        inv_norm[rid] = 1.0f / sqrtf(ss);
        pool[rid] = s * (1.0f / 441.0f);
    }
}

// ---------------- pack_all: 4 pack bodies + cosine logits ----------------
// Frag convention (16x16x32): row/col = lane&15 ; k = (lane>>4)*8 + j
__global__ __launch_bounds__(256, 4) void pack_all(const float* __restrict__ in1,
                                                   const float* __restrict__ in2,
                                                   const float* __restrict__ inv_norm,
                                                   const float* __restrict__ pool,
                                                   uint4* __restrict__ Pq,
                                                   uint4* __restrict__ Ps,
                                                   uint4* __restrict__ Al,
                                                   uint4* __restrict__ Bl,
                                                   float* __restrict__ feats) {
    int bid = blockIdx.x;
    int tid = threadIdx.x;
    unsigned short hs[8];
    if (bid < 840) {
        // Pq: B-side of ip_p. col=h=cs*16+(lane&15), k=d
        int idx = bid * 256 + tid;
        int lane = idx & 63;
        int ks = (idx >> 6) & 1;
        int rest = idx >> 7;
        int gcs = rest % 840, e = rest / 840;
        int q = gcs / 28, cs = gcs % 28;
        int h = cs * 16 + (lane & 15);
        int d0 = ks * 32 + ((lane >> 4) << 3);
        int rowq = (e * 30 + q) * 64;
#pragma unroll
        for (int j = 0; j < 8; ++j) {
            int d = d0 + j;
            float v = (h < 441) ? in1[(size_t)(rowq + d) * 441 + h] * inv_norm[rowq + d] : 0.f;
            hs[j] = to_bf16(v);
        }
        uint4 H;
        H.x = hs[0] | (hs[1] << 16); H.y = hs[2] | (hs[3] << 16);
        H.z = hs[4] | (hs[5] << 16); H.w = hs[6] | (hs[7] << 16);
        Pq[idx] = H;
    } else if (bid < 1530) {
        // Ps: A-side of ip_p. row=kidx=kt*16+(lane&15), k=d
        int idx = (bid - 840) * 256 + tid;
        int lane = idx & 63;
        int ks = (idx >> 6) & 1;
        int rest = idx >> 7;
        int kt = rest % 138, ew = rest / 138;
        int kidx = kt * 16 + (lane & 15);
        bool valid = kidx < 2205;
        int kc = valid ? kidx : 0;
        int sh = kc / 441;
        int h = kc - sh * 441;
        int e = ew / 5, w = ew % 5;
        int srow = ((e * 25 + w * 5 + sh) * 64);
        int d0 = ks * 32 + ((lane >> 4) << 3);
#pragma unroll
        for (int j = 0; j < 8; ++j) {
            int d = d0 + j;
            float v = valid ? in2[(size_t)(srow + d) * 441 + h] * inv_norm[3840 + srow + d] : 0.f;
            hs[j] = to_bf16(v);
        }
        uint4 H;
        H.x = hs[0] | (hs[1] << 16); H.y = hs[2] | (hs[3] << 16);
        H.z = hs[4] | (hs[5] << 16); H.w = hs[6] | (hs[7] << 16);
        Ps[idx] = H;
    } else if (bid < 2230) {
        // Al: A-side of ip_l. row=rt*16+(lane&15) (=sh*64+d'), k=h
        int idx = (bid - 1530) * 256 + tid;
        int lane = idx & 63;
        int t2 = idx >> 6;
        int ks = t2 % 14;
        int t3 = t2 / 14;
        int rt = t3 % 20, ew = t3 / 20;
        int e = ew / 5, w = ew % 5;
        int row = rt * 16 + (lane & 15);  // < 320
        int sh = row >> 6, dp = row & 63;
        int srow = (e * 25 + w * 5 + sh) * 64 + dp;
        int h0 = ks * 32 + ((lane >> 4) << 3);
        const float* src = in2 + (size_t)srow * 441;
        float inv = inv_norm[3840 + srow];
#pragma unroll
        for (int j = 0; j < 8; ++j) {
            int h = h0 + j;
            float v = (h < 441) ? src[h] * inv : 0.f;
            hs[j] = to_bf16(v);
        }
        uint4 H;
        H.x = hs[0] | (hs[1] << 16); H.y = hs[2] | (hs[3] << 16);
        H.z = hs[4] | (hs[5] << 16); H.w = hs[6] | (hs[7] << 16);
        Al[idx] = H;
    } else if (bid < 3070) {
        // Bl: B-side of ip_l. col=gct*16+(lane&15) (=q*64+d), k=h
        int idx = (bid - 2230) * 256 + tid;
        int lane = idx & 63;
        int t2 = idx >> 6;
        int ks = t2 % 14;
        int t3 = t2 / 14;
        int gct = t3 % 120, e = t3 / 120;
        int col = gct * 16 + (lane & 15);
        int q = col >> 6, d = col & 63;
        int qrow = (e * 30 + q) * 64 + d;
        int h0 = ks * 32 + ((lane >> 4) << 3);
        const float* src = in1 + (size_t)qrow * 441;
        float inv = inv_norm[qrow];
#pragma unroll
        for (int j = 0; j < 8; ++j) {
            int h = h0 + j;
            float v = (h < 441) ? src[h] * inv : 0.f;
            hs[j] = to_bf16(v);
        }
        uint4 H;
        H.x = hs[0] | (hs[1] << 16); H.y = hs[2] | (hs[3] << 16);
        H.z = hs[4] | (hs[5] << 16); H.w = hs[6] | (hs[7] << 16);
        Bl[idx] = H;
    } else {
        // cosine logits
        int e = bid - 3070;
        __shared__ float qp[30 * 64], pr[5 * 64], qn[30], pn[5];
        int t = tid;
        for (int li = t; li < 1920; li += 256) qp[li] = pool[e * 30 * 64 + li];
        for (int li = t; li < 320; li += 256) {
            int w = li >> 6, d = li & 63;
            float sm = 0.f;
            for (int sh = 0; sh < 5; ++sh) sm += pool[(60 + e * 25 + w * 5 + sh) * 64 + d];
            pr[li] = sm * 0.2f;
        }
        __syncthreads();
        if (t < 30) {
            float ss = 0.f;
            for (int d = 0; d < 64; ++d) { float v = qp[t * 64 + d]; ss = fmaf(v, v, ss); }
            qn[t] = 1.0f / sqrtf(ss);
        }
        if (t >= 32 && t < 37) {
            int w = t - 32; float ss = 0.f;
            for (int d = 0; d < 64; ++d) { float v = pr[w * 64 + d]; ss = fmaf(v, v, ss); }
            pn[w] = 1.0f / sqrtf(ss);
        }
        __syncthreads();
        if (t < 150) {
            int q = t / 5, w = t % 5;
            float dp = 0.f;
            for (int d = 0; d < 64; ++d) dp = fmaf(qp[q * 64 + d], pr[w * 64 + d], dp);
            feats[(e * 30 + q) * 15 + w] = dp * qn[q] * pn[w];
        }
    }
}

// channel rr-pass: NRR row-tiles, full-K accumulate, then top5-insert.
template <int NRR>
__device__ __forceinline__ void chan_pass(int rr0, int ew, int e, int q, int wv, int lane,
                                          const bf16x8* __restrict__ Bl,
                                          const bf16x8* __restrict__ Al,
                                          float m[4][5]) {
    f32x4 cc[NRR][4];
#pragma unroll
    for (int r = 0; r < NRR; ++r)
#pragma unroll
        for (int s = 0; s < 4; ++s) cc[r][s] = (f32x4){0.f, 0.f, 0.f, 0.f};
    for (int ks = 0; ks < 14; ++ks) {
        bf16x8 bh[4];
#pragma unroll
        for (int s = 0; s < 4; ++s)
            bh[s] = Bl[((e * 120 + q * 4 + s) * 14 + ks) * 64 + lane];
#pragma unroll
        for (int r = 0; r < NRR; ++r) {
            bf16x8 ah = Al[((ew * 20 + wv * 5 + rr0 + r) * 14 + ks) * 64 + lane];
#pragma unroll
            for (int s = 0; s < 4; ++s) cc[r][s] = MFMA16(ah, bh[s], cc[r][s]);
        }
    }
#pragma unroll
    for (int r = 0; r < NRR; ++r)
#pragma unroll
        for (int s = 0; s < 4; ++s)
#pragma unroll
            for (int g = 0; g < 4; ++g) ins5(m[s], cc[r][s][g]);
}

// ---------------- k56: XCD-grouped pixel + channel ----------------
// grid = 8 XCDs x 301 slots. slot<263: pixel p=xcd*263+slot (2100 active);
// block = ONE gwave, 4 waves = 4 k-quarters, merge via LDS.
// slot>=263: channel c=xcd*38+(slot-263) (300 active).
__global__ __launch_bounds__(256, 2) void k56(const bf16x8* __restrict__ Pq,
                                              const bf16x8* __restrict__ Ps,
                                              const bf16x8* __restrict__ Bl,
                                              const bf16x8* __restrict__ Al,
                                              float* __restrict__ part_p,
                                              float* __restrict__ siml) {
    __shared__ float SH[1280];     // 5 KB: pixel Msh[4][4][16][5] / channel Mred[4][64][5]
    int bid = blockIdx.x;
    int tid = threadIdx.x;
    int xcd = bid & 7;
    int slot = bid >> 3;
    int wv = tid >> 6, lane = tid & 63;
    const f32x4 ZV = {0.f, 0.f, 0.f, 0.f};

    if (slot < 263) {
        // ---- pixel: 4 k-quarter waves over one gwave ----
        int p = xcd * 263 + slot;
        if (p >= 2100) return;
        int ew = p / 210;
        int gwave = p - ew * 210;
        int e = ew / 5, w = ew - (ew / 5) * 5;
        int q = gwave / 7;
        int ct0 = gwave * 4;
        int k0 = wv * 35;
        int kend = (wv == 3) ? 138 : k0 + 35;

        bf16x8 Bh[4][2];
#pragma unroll
        for (int s = 0; s < 4; ++s)
#pragma unroll
            for (int ks = 0; ks < 2; ++ks)
                Bh[s][ks] = Pq[((e * 840 + ct0 + s) * 2 + ks) * 64 + lane];

        float m[4][5];
#pragma unroll
        for (int s = 0; s < 4; ++s)
#pragma unroll
            for (int i = 0; i < 5; ++i) m[s][i] = -1e30f;

        int rowbase = (lane >> 4) * 4;
        const bf16x8* As = Ps + (size_t)(ew * 138) * 128 + lane;

        bf16x8 a0 = As[(size_t)k0 * 128];
        bf16x8 a1 = As[(size_t)k0 * 128 + 64];
        for (int kt = k0; kt < kend; ++kt) {
            int ktn = (kt + 1 < kend) ? kt + 1 : kt;
            bf16x8 n0 = As[(size_t)ktn * 128];
            bf16x8 n1 = As[(size_t)ktn * 128 + 64];
#pragma unroll
            for (int s = 0; s < 4; ++s) {
                f32x4 cv = MFMA16(a0, Bh[s][0], ZV);
                cv = MFMA16(a1, Bh[s][1], cv);
                if (kt == 137) {
#pragma unroll
                    for (int gg = 0; gg < 4; ++gg) {
                        float v = (rowbase + gg < 13) ? cv[gg] : -1e30f;
                        ins5(m[s], v);
                    }
                } else {
#pragma unroll
                    for (int gg = 0; gg < 4; ++gg) ins5(m[s], cv[gg]);
                }
            }
            a0 = n0; a1 = n1;
        }

        // merge per-set top5 across the 4 row-quad lane groups
#pragma unroll
        for (int mask = 16; mask <= 32; mask <<= 1) {
            float ov[4][5];
#pragma unroll
            for (int s = 0; s < 4; ++s)
#pragma unroll
                for (int i = 0; i < 5; ++i) ov[s][i] = __shfl_xor(m[s][i], mask, 64);
#pragma unroll
            for (int s = 0; s < 4; ++s)
#pragma unroll
                for (int i = 0; i < 5; ++i) ins5(m[s], ov[s][i]);
        }

        // cross-quarter merge via LDS
        float (*Msh)[4][16][5] = (float (*)[4][16][5])SH;
        if (lane < 16) {
#pragma unroll
            for (int s = 0; s < 4; ++s)
#pragma unroll
                for (int i = 0; i < 5; ++i) Msh[wv][s][lane][i] = m[s][i];
        }
        __syncthreads();
        if (wv == 0) {
            int s = lane >> 4, col = lane & 15;
            float lst[5];
#pragma unroll
            for (int i = 0; i < 5; ++i) lst[i] = Msh[0][s][col][i];
#pragma unroll
            for (int w2 = 1; w2 < 4; ++w2)
#pragma unroll
                for (int i = 0; i < 5; ++i) ins5(lst, Msh[w2][s][col][i]);
            float s5 = lst[0] + lst[1] + lst[2] + lst[3] + lst[4];
            int h = ((ct0 + s) % 28) * 16 + col;
            s5 = (h < 441) ? s5 : 0.f;
#pragma unroll
            for (int mask = 1; mask <= 32; mask <<= 1) s5 += __shfl_xor(s5, mask, 64);
            if (lane == 0) {
                int sl = gwave - q * 7;
                part_p[((e * 30 + q) * 5 + w) * 7 + sl] = s5;
            }
        }
    } else {
        // ---- channel ----
        float (*Mred)[64][5] = (float (*)[64][5])SH;
        int c = xcd * 38 + (slot - 263);
        if (c >= 300) return;
        int ew = c / 30, q = c - ew * 30;
        int e = ew / 5, w = ew - (ew / 5) * 5;

        float m[4][5];
#pragma unroll
        for (int s = 0; s < 4; ++s)
#pragma unroll
            for (int i = 0; i < 5; ++i) m[s][i] = -1e30f;

        chan_pass<3>(0, ew, e, q, wv, lane, Bl, Al, m);
        chan_pass<2>(3, ew, e, q, wv, lane, Bl, Al, m);

#pragma unroll
        for (int mask = 16; mask <= 32; mask <<= 1) {
            float ov[4][5];
#pragma unroll
            for (int s = 0; s < 4; ++s)
#pragma unroll
                for (int i = 0; i < 5; ++i) ov[s][i] = __shfl_xor(m[s][i], mask, 64);
#pragma unroll
            for (int s = 0; s < 4; ++s)
#pragma unroll
                for (int i = 0; i < 5; ++i) ins5(m[s], ov[s][i]);
        }

        if (lane < 16) {
#pragma unroll
            for (int s = 0; s < 4; ++s)
#pragma unroll
                for (int i = 0; i < 5; ++i) Mred[wv][s * 16 + lane][i] = m[s][i];
        }
        __syncthreads();

        if (tid < 64) {
            float lst[5];
#pragma unroll
            for (int i = 0; i < 5; ++i) lst[i] = Mred[0][tid][i];
#pragma unroll
            for (int v2 = 1; v2 < 4; ++v2)
#pragma unroll
                for (int i = 0; i < 5; ++i) ins5(lst, Mred[v2][tid][i]);
            float s5 = lst[0] + lst[1] + lst[2] + lst[3] + lst[4];
#pragma unroll
            for (int mask = 1; mask <= 32; mask <<= 1) s5 += __shfl_xor(s5, mask, 64);
            if (tid == 0) siml[(e * 30 + q) * 5 + w] = s5;
        }
    }
}

// ---------------- k7: BN (episode stats) + dilated conv ----------------
__global__ __launch_bounds__(256) void k7_final(const float* __restrict__ feats,
                                                const float* __restrict__ siml,
                                                const float* __restrict__ part_p,
                                                const float* __restrict__ gamma,
                                                const float* __restrict__ beta,
                                                const float* __restrict__ convw,
                                                float* __restrict__ out) {
    int e = blockIdx.x;
    __shared__ float f[30 * 15], mu[15], inv[15];
    int t = threadIdx.x;
    if (t < 150) {
        int q = t / 5, w = t % 5;
        int pb = ((e * 30 + q) * 5 + w) * 7;
        float sp = 0.f;
#pragma unroll
        for (int s = 0; s < 7; ++s) sp += part_p[pb + s];
        f[q * 15 + w] = feats[(e * 30 + q) * 15 + w];
        f[q * 15 + 5 + w] = siml[(e * 30 + q) * 5 + w];
        f[q * 15 + 10 + w] = sp;
    }
    __syncthreads();
    if (t < 15) {
        float s1 = 0.f;
        for (int q = 0; q < 30; ++q) s1 += f[q * 15 + t];
        float mn = s1 * (1.0f / 30.0f);
        float s2 = 0.f;
        for (int q = 0; q < 30; ++q) { float d = f[q * 15 + t] - mn; s2 = fmaf(d, d, s2); }
        mu[t] = mn;
        inv[t] = 1.0f / sqrtf(s2 * (1.0f / 30.0f) + 1e-5f);
    }
    __syncthreads();
    if (t < 150) {
        int q = t / 5, j = t % 5;
        float w0 = convw[0], w1 = convw[1], w2 = convw[2];
        float b0 = (f[q * 15 + j]      - mu[j])      * inv[j]      * gamma[j]      + beta[j];
        float b1 = (f[q * 15 + 5 + j]  - mu[5 + j])  * inv[5 + j]  * gamma[5 + j]  + beta[5 + j];
        float b2 = (f[q * 15 + 10 + j] - mu[10 + j]) * inv[10 + j] * gamma[10 + j] + beta[10 + j];
        out[e * 150 + q * 5 + j] = w0 * b0 + w1 * b1 + w2 * b2;
    }
}

extern "C" void kernel_launch(void* const* d_in, const int* in_sizes, int n_in,
                              void* d_out, int out_size, void* d_ws, size_t ws_size,
                              hipStream_t stream) {
    const float* in1 = (const float*)d_in[0];
    const float* in2 = (const float*)d_in[1];
    const float* gamma = (const float*)d_in[2];
    const float* beta = (const float*)d_in[3];
    const float* convw = (const float*)d_in[4];
    float* out = (float*)d_out;

    char* ws = (char*)d_ws;
    float* inv_norm = (float*)(ws + 0);                    //  28,160 B
    float* pool     = (float*)(ws + 28160);                //  28,160 B
    float* feats    = (float*)(ws + 56320);                //   3,600 B
    float* siml     = (float*)(ws + 59920);                //   1,200 B
    float* part_p   = (float*)(ws + 61120);                //   8,400 B
    size_t o = 69520;
    uint4* Pq = (uint4*)(ws + o); o += 3440640;
    uint4* Ps = (uint4*)(ws + o); o += 2826240;
    uint4* Al = (uint4*)(ws + o); o += 2867200;
    uint4* Bl = (uint4*)(ws + o); o += 3440640;   // total ~12.7 MB

    k1_rownorm<<<dim3(1760), dim3(256), 0, stream>>>(in1, in2, inv_norm, pool);
    pack_all<<<dim3(3072), dim3(256), 0, stream>>>(in1, in2, inv_norm, pool,
                                                   Pq, Ps, Al, Bl, feats);
    k56<<<dim3(2408), dim3(256), 0, stream>>>((const bf16x8*)Pq, (const bf16x8*)Ps,
                                              (const bf16x8*)Bl, (const bf16x8*)Al,
                                              part_p, siml);
    k7_final<<<dim3(2), dim3(256), 0, stream>>>(feats, siml, part_p, gamma, beta, convw, out);
}

// Round 13
// 127.301 us; speedup vs baseline: 1.0289x; 1.0289x over previous
//
#include <hip/hip_runtime.h>
#include <math.h>

// B=2, WAY=5, SHOT=5, K=5, Q=30, DIM=64, HW=441
// Single-bf16 MFMA (16x16x32).
//  ip_p: per (e,w): C^T[k=sh*441+h (2208)][cols=(q,h) 448/q], K=d(64)
//  ip_l: per (e,w): C^T[k=sh*64+d' (320)][cols=(q,d) 1920], K=h(448)
// R13: k56 split into k6_pix + k5_chan (rocprof attribution). Pixel uses a
// modulo-3 NAMED-BANK pipeline: bank consumed at kt was loaded at kt-3, so
// the compiler can emit counted vmcnt (wait-distance 3 iters ~900cyc).
// R5-R12 all waited on the NEWEST load (rotation copy / same-iter staging)
// -> ~1000 cyc/wave-kt, explaining the invariant ~115us wall.

typedef __attribute__((ext_vector_type(8))) short bf16x8;
typedef __attribute__((ext_vector_type(4))) float f32x4;

#define MFMA16(a, b, c) __builtin_amdgcn_mfma_f32_16x16x32_bf16((a), (b), (c), 0, 0, 0)

__device__ __forceinline__ unsigned short to_bf16(float v) {
    unsigned int u = __float_as_uint(v);
    unsigned int r = u + 0x7FFFu + ((u >> 16) & 1u);
    return (unsigned short)(r >> 16);
}

// sorted-desc top5 insert via v_med3_f32: 5 VALU ops.
__device__ __forceinline__ void ins5(float m[5], float v) {
    m[4] = __builtin_amdgcn_fmed3f(v, m[4], m[3]);
    m[3] = __builtin_amdgcn_fmed3f(v, m[3], m[2]);
    m[2] = __builtin_amdgcn_fmed3f(v, m[2], m[1]);
    m[1] = __builtin_amdgcn_fmed3f(v, m[1], m[0]);
    m[0] = fmaxf(m[0], v);
}

// ---------------- k1: row norms + row means ----------------
__global__ __launch_bounds__(256) void k1_rownorm(const float* __restrict__ in1,
                                                  const float* __restrict__ in2,
                                                  float* __restrict__ inv_norm,
                                                  float* __restrict__ pool) {
    int wv = threadIdx.x >> 6;
    int lane = threadIdx.x & 63;
    int rid = blockIdx.x * 4 + wv;  // 0..7039
    const float* src = (rid < 3840) ? (in1 + (size_t)rid * 441)
                                    : (in2 + (size_t)(rid - 3840) * 441);
    float s = 0.f, ss = 0.f;
#pragma unroll
    for (int i = 0; i < 7; ++i) {
        int h = lane + i * 64;
        if (h < 441) { float v = src[h]; s += v; ss = fmaf(v, v, ss); }
    }
#pragma unroll
    for (int off = 32; off > 0; off >>= 1) {
        s += __shfl_xor(s, off, 64);
        ss += __shfl_xor(ss, off, 64);
    }
    if (lane == 0) {
        inv_norm[rid] = 1.0f / sqrtf(ss);
        pool[rid] = s * (1.0f / 441.0f);
    }
}

// ---------------- pack_all: 4 pack bodies + cosine logits ----------------
// Frag convention (16x16x32): row/col = lane&15 ; k = (lane>>4)*8 + j
__global__ __launch_bounds__(256, 4) void pack_all(const float* __restrict__ in1,
                                                   const float* __restrict__ in2,
                                                   const float* __restrict__ inv_norm,
                                                   const float* __restrict__ pool,
                                                   uint4* __restrict__ Pq,
                                                   uint4* __restrict__ Ps,
                                                   uint4* __restrict__ Al,
                                                   uint4* __restrict__ Bl,
                                                   float* __restrict__ feats) {
    int bid = blockIdx.x;
    int tid = threadIdx.x;
    unsigned short hs[8];
    if (bid < 840) {
        // Pq: B-side of ip_p. col=h=cs*16+(lane&15), k=d
        int idx = bid * 256 + tid;
        int lane = idx & 63;
        int ks = (idx >> 6) & 1;
        int rest = idx >> 7;
        int gcs = rest % 840, e = rest / 840;
        int q = gcs / 28, cs = gcs % 28;
        int h = cs * 16 + (lane & 15);
        int d0 = ks * 32 + ((lane >> 4) << 3);
        int rowq = (e * 30 + q) * 64;
#pragma unroll
        for (int j = 0; j < 8; ++j) {
            int d = d0 + j;
            float v = (h < 441) ? in1[(size_t)(rowq + d) * 441 + h] * inv_norm[rowq + d] : 0.f;
            hs[j] = to_bf16(v);
        }
        uint4 H;
        H.x = hs[0] | (hs[1] << 16); H.y = hs[2] | (hs[3] << 16);
        H.z = hs[4] | (hs[5] << 16); H.w = hs[6] | (hs[7] << 16);
        Pq[idx] = H;
    } else if (bid < 1530) {
        // Ps: A-side of ip_p. row=kidx=kt*16+(lane&15), k=d
        int idx = (bid - 840) * 256 + tid;
        int lane = idx & 63;
        int ks = (idx >> 6) & 1;
        int rest = idx >> 7;
        int kt = rest % 138, ew = rest / 138;
        int kidx = kt * 16 + (lane & 15);
        bool valid = kidx < 2205;
        int kc = valid ? kidx : 0;
        int sh = kc / 441;
        int h = kc - sh * 441;
        int e = ew / 5, w = ew % 5;
        int srow = ((e * 25 + w * 5 + sh) * 64);
        int d0 = ks * 32 + ((lane >> 4) << 3);
#pragma unroll
        for (int j = 0; j < 8; ++j) {
            int d = d0 + j;
            float v = valid ? in2[(size_t)(srow + d) * 441 + h] * inv_norm[3840 + srow + d] : 0.f;
            hs[j] = to_bf16(v);
        }
        uint4 H;
        H.x = hs[0] | (hs[1] << 16); H.y = hs[2] | (hs[3] << 16);
        H.z = hs[4] | (hs[5] << 16); H.w = hs[6] | (hs[7] << 16);
        Ps[idx] = H;
    } else if (bid < 2230) {
        // Al: A-side of ip_l. row=rt*16+(lane&15) (=sh*64+d'), k=h
        int idx = (bid - 1530) * 256 + tid;
        int lane = idx & 63;
        int t2 = idx >> 6;
        int ks = t2 % 14;
        int t3 = t2 / 14;
        int rt = t3 % 20, ew = t3 / 20;
        int e = ew / 5, w = ew % 5;
        int row = rt * 16 + (lane & 15);  // < 320
        int sh = row >> 6, dp = row & 63;
        int srow = (e * 25 + w * 5 + sh) * 64 + dp;
        int h0 = ks * 32 + ((lane >> 4) << 3);
        const float* src = in2 + (size_t)srow * 441;
        float inv = inv_norm[3840 + srow];
#pragma unroll
        for (int j = 0; j < 8; ++j) {
            int h = h0 + j;
            float v = (h < 441) ? src[h] * inv : 0.f;
            hs[j] = to_bf16(v);
        }
        uint4 H;
        H.x = hs[0] | (hs[1] << 16); H.y = hs[2] | (hs[3] << 16);
        H.z = hs[4] | (hs[5] << 16); H.w = hs[6] | (hs[7] << 16);
        Al[idx] = H;
    } else if (bid < 3070) {
        // Bl: B-side of ip_l. col=gct*16+(lane&15) (=q*64+d), k=h
        int idx = (bid - 2230) * 256 + tid;
        int lane = idx & 63;
        int t2 = idx >> 6;
        int ks = t2 % 14;
        int t3 = t2 / 14;
        int gct = t3 % 120, e = t3 / 120;
        int col = gct * 16 + (lane & 15);
        int q = col >> 6, d = col & 63;
        int qrow = (e * 30 + q) * 64 + d;
        int h0 = ks * 32 + ((lane >> 4) << 3);
        const float* src = in1 + (size_t)qrow * 441;
        float inv = inv_norm[qrow];
#pragma unroll
        for (int j = 0; j < 8; ++j) {
            int h = h0 + j;
            float v = (h < 441) ? src[h] * inv : 0.f;
            hs[j] = to_bf16(v);
        }
        uint4 H;
        H.x = hs[0] | (hs[1] << 16); H.y = hs[2] | (hs[3] << 16);
        H.z = hs[4] | (hs[5] << 16); H.w = hs[6] | (hs[7] << 16);
        Bl[idx] = H;
    } else {
        // cosine logits
        int e = bid - 3070;
        __shared__ float qp[30 * 64], pr[5 * 64], qn[30], pn[5];
        int t = tid;
        for (int li = t; li < 1920; li += 256) qp[li] = pool[e * 30 * 64 + li];
        for (int li = t; li < 320; li += 256) {
            int w = li >> 6, d = li & 63;
            float sm = 0.f;
            for (int sh = 0; sh < 5; ++sh) sm += pool[(60 + e * 25 + w * 5 + sh) * 64 + d];
            pr[li] = sm * 0.2f;
        }
        __syncthreads();
        if (t < 30) {
            float ss = 0.f;
            for (int d = 0; d < 64; ++d) { float v = qp[t * 64 + d]; ss = fmaf(v, v, ss); }
            qn[t] = 1.0f / sqrtf(ss);
        }
        if (t >= 32 && t < 37) {
            int w = t - 32; float ss = 0.f;
            for (int d = 0; d < 64; ++d) { float v = pr[w * 64 + d]; ss = fmaf(v, v, ss); }
            pn[w] = 1.0f / sqrtf(ss);
        }
        __syncthreads();
        if (t < 150) {
            int q = t / 5, w = t % 5;
            float dp = 0.f;
            for (int d = 0; d < 64; ++d) dp = fmaf(qp[q * 64 + d], pr[w * 64 + d], dp);
            feats[(e * 30 + q) * 15 + w] = dp * qn[q] * pn[w];
        }
    }
}

// ---------------- k6_pix: pixel similarity, modulo-3 named-bank pipeline ----
// grid = 8 XCDs x 263 slots; p = xcd*263+slot (2100 active); block = one
// gwave x 4 k-quarter waves (36/36/36/30 kt); cross-quarter merge via LDS.
#define PIXBODY(X0, X1, KIDX)                                              \
    do {                                                                   \
        _Pragma("unroll")                                                  \
        for (int s = 0; s < 4; ++s) {                                      \
            f32x4 cv = MFMA16(X0, Bh[s][0], ZV);                           \
            cv = MFMA16(X1, Bh[s][1], cv);                                 \
            _Pragma("unroll")                                              \
            for (int gg = 0; gg < 4; ++gg) ins5(m[s], cv[gg]);             \
        }                                                                  \
        X0 = As[(size_t)((KIDX) + 3) * 128];                               \
        X1 = As[(size_t)((KIDX) + 3) * 128 + 64];                          \
    } while (0)

#define PIXTAIL(X0, X1, KIDX)                                              \
    do {                                                                   \
        bool lastk = ((KIDX) == 137);                                      \
        _Pragma("unroll")                                                  \
        for (int s = 0; s < 4; ++s) {                                      \
            f32x4 cv = MFMA16(X0, Bh[s][0], ZV);                           \
            cv = MFMA16(X1, Bh[s][1], cv);                                 \
            _Pragma("unroll")                                              \
            for (int gg = 0; gg < 4; ++gg) {                               \
                float v = (lastk && (rowbase + gg >= 13)) ? -1e30f : cv[gg]; \
                ins5(m[s], v);                                             \
            }                                                              \
        }                                                                  \
    } while (0)

__global__ __launch_bounds__(256, 2) void k6_pix(const bf16x8* __restrict__ Pq,
                                                 const bf16x8* __restrict__ Ps,
                                                 float* __restrict__ part_p) {
    __shared__ float SH[1280];     // Msh[4][4][16][5]
    int bid = blockIdx.x;
    int tid = threadIdx.x;
    int xcd = bid & 7;
    int slot = bid >> 3;
    int wv = tid >> 6, lane = tid & 63;
    const f32x4 ZV = {0.f, 0.f, 0.f, 0.f};

    int p = xcd * 263 + slot;
    if (p >= 2100) return;
    int ew = p / 210;
    int gwave = p - ew * 210;
    int e = ew / 5, w = ew - (ew / 5) * 5;
    int q = gwave / 7;
    int ct0 = gwave * 4;
    int k0 = wv * 36;
    int kend = (wv == 3) ? 138 : k0 + 36;
    int T = (kend - k0 - 3) / 3;       // 11 or 9

    bf16x8 Bh[4][2];
#pragma unroll
    for (int s = 0; s < 4; ++s)
#pragma unroll
        for (int ks = 0; ks < 2; ++ks)
            Bh[s][ks] = Pq[((e * 840 + ct0 + s) * 2 + ks) * 64 + lane];

    float m[4][5];
#pragma unroll
    for (int s = 0; s < 4; ++s)
#pragma unroll
        for (int i = 0; i < 5; ++i) m[s][i] = -1e30f;

    int rowbase = (lane >> 4) * 4;
    const bf16x8* As = Ps + (size_t)(ew * 138) * 128 + lane;

    // prologue: 3 banks in flight
    bf16x8 a0 = As[(size_t)(k0 + 0) * 128], a1 = As[(size_t)(k0 + 0) * 128 + 64];
    bf16x8 b0 = As[(size_t)(k0 + 1) * 128], b1 = As[(size_t)(k0 + 1) * 128 + 64];
    bf16x8 c0 = As[(size_t)(k0 + 2) * 128], c1 = As[(size_t)(k0 + 2) * 128 + 64];

    int kt = k0;
    for (int i = 0; i < T; ++i) {
        PIXBODY(a0, a1, kt);
        PIXBODY(b0, b1, kt + 1);
        PIXBODY(c0, c1, kt + 2);
        kt += 3;
    }
    // epilogue: consume the 3 preloaded banks (kend-3..kend-1)
    PIXTAIL(a0, a1, kt);
    PIXTAIL(b0, b1, kt + 1);
    PIXTAIL(c0, c1, kt + 2);

    // merge per-set top5 across the 4 row-quad lane groups
#pragma unroll
    for (int mask = 16; mask <= 32; mask <<= 1) {
        float ov[4][5];
#pragma unroll
        for (int s = 0; s < 4; ++s)
#pragma unroll
            for (int i = 0; i < 5; ++i) ov[s][i] = __shfl_xor(m[s][i], mask, 64);
#pragma unroll
        for (int s = 0; s < 4; ++s)
#pragma unroll
            for (int i = 0; i < 5; ++i) ins5(m[s], ov[s][i]);
    }

    // cross-quarter merge via LDS
    float (*Msh)[4][16][5] = (float (*)[4][16][5])SH;
    if (lane < 16) {
#pragma unroll
        for (int s = 0; s < 4; ++s)
#pragma unroll
            for (int i = 0; i < 5; ++i) Msh[wv][s][lane][i] = m[s][i];
    }
    __syncthreads();
    if (wv == 0) {
        int s = lane >> 4, col = lane & 15;
        float lst[5];
#pragma unroll
        for (int i = 0; i < 5; ++i) lst[i] = Msh[0][s][col][i];
#pragma unroll
        for (int w2 = 1; w2 < 4; ++w2)
#pragma unroll
            for (int i = 0; i < 5; ++i) ins5(lst, Msh[w2][s][col][i]);
        float s5 = lst[0] + lst[1] + lst[2] + lst[3] + lst[4];
        int h = ((ct0 + s) % 28) * 16 + col;
        s5 = (h < 441) ? s5 : 0.f;
#pragma unroll
        for (int mask = 1; mask <= 32; mask <<= 1) s5 += __shfl_xor(s5, mask, 64);
        if (lane == 0) {
            int sl = gwave - q * 7;
            part_p[((e * 30 + q) * 5 + w) * 7 + sl] = s5;
        }
    }
}

// channel rr-pass: NRR row-tiles, full-K accumulate, then top5-insert.
template <int NRR>
__device__ __forceinline__ void chan_pass(int rr0, int ew, int e, int q, int wv, int lane,
                                          const bf16x8* __restrict__ Bl,
                                          const bf16x8* __restrict__ Al,
                                          float m[4][5]) {
    f32x4 cc[NRR][4];
#pragma unroll
    for (int r = 0; r < NRR; ++r)
#pragma unroll
        for (int s = 0; s < 4; ++s) cc[r][s] = (f32x4){0.f, 0.f, 0.f, 0.f};
    for (int ks = 0; ks < 14; ++ks) {
        bf16x8 bh[4];
#pragma unroll
        for (int s = 0; s < 4; ++s)
            bh[s] = Bl[((e * 120 + q * 4 + s) * 14 + ks) * 64 + lane];
#pragma unroll
        for (int r = 0; r < NRR; ++r) {
            bf16x8 ah = Al[((ew * 20 + wv * 5 + rr0 + r) * 14 + ks) * 64 + lane];
#pragma unroll
            for (int s = 0; s < 4; ++s) cc[r][s] = MFMA16(ah, bh[s], cc[r][s]);
        }
    }
#pragma unroll
    for (int r = 0; r < NRR; ++r)
#pragma unroll
        for (int s = 0; s < 4; ++s)
#pragma unroll
            for (int g = 0; g < 4; ++g) ins5(m[s], cc[r][s][g]);
}

// ---------------- k5_chan: channel similarity (separate for attribution) ----
__global__ __launch_bounds__(256, 2) void k5_chan(const bf16x8* __restrict__ Bl,
                                                  const bf16x8* __restrict__ Al,
                                                  float* __restrict__ siml) {
    __shared__ float Mred[4][64][5];
    int bid = blockIdx.x;
    int tid = threadIdx.x;
    int xcd = bid & 7;
    int slot = bid >> 3;
    int wv = tid >> 6, lane = tid & 63;

    int c = xcd * 38 + slot;
    if (c >= 300) return;
    int ew = c / 30, q = c - ew * 30;
    int e = ew / 5, w = ew - (ew / 5) * 5;

    float m[4][5];
#pragma unroll
    for (int s = 0; s < 4; ++s)
#pragma unroll
        for (int i = 0; i < 5; ++i) m[s][i] = -1e30f;

    chan_pass<3>(0, ew, e, q, wv, lane, Bl, Al, m);
    chan_pass<2>(3, ew, e, q, wv, lane, Bl, Al, m);

#pragma unroll
    for (int mask = 16; mask <= 32; mask <<= 1) {
        float ov[4][5];
#pragma unroll
        for (int s = 0; s < 4; ++s)
#pragma unroll
            for (int i = 0; i < 5; ++i) ov[s][i] = __shfl_xor(m[s][i], mask, 64);
#pragma unroll
        for (int s = 0; s < 4; ++s)
#pragma unroll
            for (int i = 0; i < 5; ++i) ins5(m[s], ov[s][i]);
    }

    if (lane < 16) {
#pragma unroll
        for (int s = 0; s < 4; ++s)
#pragma unroll
            for (int i = 0; i < 5; ++i) Mred[wv][s * 16 + lane][i] = m[s][i];
    }
    __syncthreads();

    if (tid < 64) {
        float lst[5];
#pragma unroll
        for (int i = 0; i < 5; ++i) lst[i] = Mred[0][tid][i];
#pragma unroll
        for (int v2 = 1; v2 < 4; ++v2)
#pragma unroll
            for (int i = 0; i < 5; ++i) ins5(lst, Mred[v2][tid][i]);
        float s5 = lst[0] + lst[1] + lst[2] + lst[3] + lst[4];
#pragma unroll
        for (int mask = 1; mask <= 32; mask <<= 1) s5 += __shfl_xor(s5, mask, 64);
        if (tid == 0) siml[(e * 30 + q) * 5 + w] = s5;
    }
}

// ---------------- k7: BN (episode stats) + dilated conv ----------------
__global__ __launch_bounds__(256) void k7_final(const float* __restrict__ feats,
                                                const float* __restrict__ siml,
                                                const float* __restrict__ part_p,
                                                const float* __restrict__ gamma,
                                                const float* __restrict__ beta,
                                                const float* __restrict__ convw,
                                                float* __restrict__ out) {
    int e = blockIdx.x;
    __shared__ float f[30 * 15], mu[15], inv[15];
    int t = threadIdx.x;
    if (t < 150) {
        int q = t / 5, w = t % 5;
        int pb = ((e * 30 + q) * 5 + w) * 7;
        float sp = 0.f;
#pragma unroll
        for (int s = 0; s < 7; ++s) sp += part_p[pb + s];
        f[q * 15 + w] = feats[(e * 30 + q) * 15 + w];
        f[q * 15 + 5 + w] = siml[(e * 30 + q) * 5 + w];
        f[q * 15 + 10 + w] = sp;
    }
    __syncthreads();
    if (t < 15) {
        float s1 = 0.f;
        for (int q = 0; q < 30; ++q) s1 += f[q * 15 + t];
        float mn = s1 * (1.0f / 30.0f);
        float s2 = 0.f;
        for (int q = 0; q < 30; ++q) { float d = f[q * 15 + t] - mn; s2 = fmaf(d, d, s2); }
        mu[t] = mn;
        inv[t] = 1.0f / sqrtf(s2 * (1.0f / 30.0f) + 1e-5f);
    }
    __syncthreads();
    if (t < 150) {
        int q = t / 5, j = t % 5;
        float w0 = convw[0], w1 = convw[1], w2 = convw[2];
        float b0 = (f[q * 15 + j]      - mu[j])      * inv[j]      * gamma[j]      + beta[j];
        float b1 = (f[q * 15 + 5 + j]  - mu[5 + j])  * inv[5 + j]  * gamma[5 + j]  + beta[5 + j];
        float b2 = (f[q * 15 + 10 + j] - mu[10 + j]) * inv[10 + j] * gamma[10 + j] + beta[10 + j];
        out[e * 150 + q * 5 + j] = w0 * b0 + w1 * b1 + w2 * b2;
    }
}

extern "C" void kernel_launch(void* const* d_in, const int* in_sizes, int n_in,
                              void* d_out, int out_size, void* d_ws, size_t ws_size,
                              hipStream_t stream) {
    const float* in1 = (const float*)d_in[0];
    const float* in2 = (const float*)d_in[1];
    const float* gamma = (const float*)d_in[2];
    const float* beta = (const float*)d_in[3];
    const float* convw = (const float*)d_in[4];
    float* out = (float*)d_out;

    char* ws = (char*)d_ws;
    float* inv_norm = (float*)(ws + 0);                    //  28,160 B
    float* pool     = (float*)(ws + 28160);                //  28,160 B
    float* feats    = (float*)(ws + 56320);                //   3,600 B
    float* siml     = (float*)(ws + 59920);                //   1,200 B
    float* part_p   = (float*)(ws + 61120);                //   8,400 B
    size_t o = 69520;
    uint4* Pq = (uint4*)(ws + o); o += 3440640;
    uint4* Ps = (uint4*)(ws + o); o += 2826240;
    uint4* Al = (uint4*)(ws + o); o += 2867200;
    uint4* Bl = (uint4*)(ws + o); o += 3440640;   // total ~12.7 MB

    k1_rownorm<<<dim3(1760), dim3(256), 0, stream>>>(in1, in2, inv_norm, pool);
    pack_all<<<dim3(3072), dim3(256), 0, stream>>>(in1, in2, inv_norm, pool,
                                                   Pq, Ps, Al, Bl, feats);
    k6_pix<<<dim3(2104), dim3(256), 0, stream>>>((const bf16x8*)Pq, (const bf16x8*)Ps,
                                                 part_p);
    k5_chan<<<dim3(304), dim3(256), 0, stream>>>((const bf16x8*)Bl, (const bf16x8*)Al,
                                                 siml);
    k7_final<<<dim3(2), dim3(256), 0, stream>>>(feats, siml, part_p, gamma, beta, convw, out);
}

// Round 14
// 125.395 us; speedup vs baseline: 1.0445x; 1.0152x over previous
//
#include <hip/hip_runtime.h>
#include <math.h>

// B=2, WAY=5, SHOT=5, K=5, Q=30, DIM=64, HW=441
// Single-bf16 MFMA (16x16x32).
//  ip_p: per (e,w): C^T[k=sh*441+h (2208)][cols=(q,h) 448/q], K=d(64)
//  ip_l: per (e,w): C^T[k=sh*64+d' (320)][cols=(q,d) 1920], K=h(448)
// R14 = R13 + amdgpu_waves_per_eu(4,4) on k6_pix/k5_chan. R13 diagnosis:
// VGPR_Count=52 << working set => Bh/cv went to AGPRs (unified file),
// total regs ~160/wave => ~2.5 waves/SIMD (Occ 32%); every pipe ~20% busy
// per-SIMD (VALUBusy 69% is CU-level OR of 4 SIMDs). Pinning waves/EU to
// exactly 4 gives the allocator a 128-reg budget (demand ~104, no spill)
// and doubles resident waves for latency hiding.

typedef __attribute__((ext_vector_type(8))) short bf16x8;
typedef __attribute__((ext_vector_type(4))) float f32x4;

#define MFMA16(a, b, c) __builtin_amdgcn_mfma_f32_16x16x32_bf16((a), (b), (c), 0, 0, 0)

__device__ __forceinline__ unsigned short to_bf16(float v) {
    unsigned int u = __float_as_uint(v);
    unsigned int r = u + 0x7FFFu + ((u >> 16) & 1u);
    return (unsigned short)(r >> 16);
}

// sorted-desc top5 insert via v_med3_f32: 5 VALU ops, all reading OLD state.
__device__ __forceinline__ void ins5(float m[5], float v) {
    m[4] = __builtin_amdgcn_fmed3f(v, m[4], m[3]);
    m[3] = __builtin_amdgcn_fmed3f(v, m[3], m[2]);
    m[2] = __builtin_amdgcn_fmed3f(v, m[2], m[1]);
    m[1] = __builtin_amdgcn_fmed3f(v, m[1], m[0]);
    m[0] = fmaxf(m[0], v);
}

// ---------------- k1: row norms + row means ----------------
__global__ __launch_bounds__(256) void k1_rownorm(const float* __restrict__ in1,
                                                  const float* __restrict__ in2,
                                                  float* __restrict__ inv_norm,
                                                  float* __restrict__ pool) {
    int wv = threadIdx.x >> 6;
    int lane = threadIdx.x & 63;
    int rid = blockIdx.x * 4 + wv;  // 0..7039
    const float* src = (rid < 3840) ? (in1 + (size_t)rid * 441)
                                    : (in2 + (size_t)(rid - 3840) * 441);
    float s = 0.f, ss = 0.f;
#pragma unroll
    for (int i = 0; i < 7; ++i) {
        int h = lane + i * 64;
        if (h < 441) { float v = src[h]; s += v; ss = fmaf(v, v, ss); }
    }
#pragma unroll
    for (int off = 32; off > 0; off >>= 1) {
        s += __shfl_xor(s, off, 64);
        ss += __shfl_xor(ss, off, 64);
    }
    if (lane == 0) {
        inv_norm[rid] = 1.0f / sqrtf(ss);
        pool[rid] = s * (1.0f / 441.0f);
    }
}

// ---------------- pack_all: 4 pack bodies + cosine logits ----------------
// Frag convention (16x16x32): row/col = lane&15 ; k = (lane>>4)*8 + j
__global__ __launch_bounds__(256, 4) void pack_all(const float* __restrict__ in1,
                                                   const float* __restrict__ in2,
                                                   const float* __restrict__ inv_norm,
                                                   const float* __restrict__ pool,
                                                   uint4* __restrict__ Pq,
                                                   uint4* __restrict__ Ps,
                                                   uint4* __restrict__ Al,
                                                   uint4* __restrict__ Bl,
                                                   float* __restrict__ feats) {
    int bid = blockIdx.x;
    int tid = threadIdx.x;
    unsigned short hs[8];
    if (bid < 840) {
        // Pq: B-side of ip_p. col=h=cs*16+(lane&15), k=d
        int idx = bid * 256 + tid;
        int lane = idx & 63;
        int ks = (idx >> 6) & 1;
        int rest = idx >> 7;
        int gcs = rest % 840, e = rest / 840;
        int q = gcs / 28, cs = gcs % 28;
        int h = cs * 16 + (lane & 15);
        int d0 = ks * 32 + ((lane >> 4) << 3);
        int rowq = (e * 30 + q) * 64;
#pragma unroll
        for (int j = 0; j < 8; ++j) {
            int d = d0 + j;
            float v = (h < 441) ? in1[(size_t)(rowq + d) * 441 + h] * inv_norm[rowq + d] : 0.f;
            hs[j] = to_bf16(v);
        }
        uint4 H;
        H.x = hs[0] | (hs[1] << 16); H.y = hs[2] | (hs[3] << 16);
        H.z = hs[4] | (hs[5] << 16); H.w = hs[6] | (hs[7] << 16);
        Pq[idx] = H;
    } else if (bid < 1530) {
        // Ps: A-side of ip_p. row=kidx=kt*16+(lane&15), k=d
        int idx = (bid - 840) * 256 + tid;
        int lane = idx & 63;
        int ks = (idx >> 6) & 1;
        int rest = idx >> 7;
        int kt = rest % 138, ew = rest / 138;
        int kidx = kt * 16 + (lane & 15);
        bool valid = kidx < 2205;
        int kc = valid ? kidx : 0;
        int sh = kc / 441;
        int h = kc - sh * 441;
        int e = ew / 5, w = ew % 5;
        int srow = ((e * 25 + w * 5 + sh) * 64);
        int d0 = ks * 32 + ((lane >> 4) << 3);
#pragma unroll
        for (int j = 0; j < 8; ++j) {
            int d = d0 + j;
            float v = valid ? in2[(size_t)(srow + d) * 441 + h] * inv_norm[3840 + srow + d] : 0.f;
            hs[j] = to_bf16(v);
        }
        uint4 H;
        H.x = hs[0] | (hs[1] << 16); H.y = hs[2] | (hs[3] << 16);
        H.z = hs[4] | (hs[5] << 16); H.w = hs[6] | (hs[7] << 16);
        Ps[idx] = H;
    } else if (bid < 2230) {
        // Al: A-side of ip_l. row=rt*16+(lane&15) (=sh*64+d'), k=h
        int idx = (bid - 1530) * 256 + tid;
        int lane = idx & 63;
        int t2 = idx >> 6;
        int ks = t2 % 14;
        int t3 = t2 / 14;
        int rt = t3 % 20, ew = t3 / 20;
        int e = ew / 5, w = ew % 5;
        int row = rt * 16 + (lane & 15);  // < 320
        int sh = row >> 6, dp = row & 63;
        int srow = (e * 25 + w * 5 + sh) * 64 + dp;
        int h0 = ks * 32 + ((lane >> 4) << 3);
        const float* src = in2 + (size_t)srow * 441;
        float inv = inv_norm[3840 + srow];
#pragma unroll
        for (int j = 0; j < 8; ++j) {
            int h = h0 + j;
            float v = (h < 441) ? src[h] * inv : 0.f;
            hs[j] = to_bf16(v);
        }
        uint4 H;
        H.x = hs[0] | (hs[1] << 16); H.y = hs[2] | (hs[3] << 16);
        H.z = hs[4] | (hs[5] << 16); H.w = hs[6] | (hs[7] << 16);
        Al[idx] = H;
    } else if (bid < 3070) {
        // Bl: B-side of ip_l. col=gct*16+(lane&15) (=q*64+d), k=h
        int idx = (bid - 2230) * 256 + tid;
        int lane = idx & 63;
        int t2 = idx >> 6;
        int ks = t2 % 14;
        int t3 = t2 / 14;
        int gct = t3 % 120, e = t3 / 120;
        int col = gct * 16 + (lane & 15);
        int q = col >> 6, d = col & 63;
        int qrow = (e * 30 + q) * 64 + d;
        int h0 = ks * 32 + ((lane >> 4) << 3);
        const float* src = in1 + (size_t)qrow * 441;
        float inv = inv_norm[qrow];
#pragma unroll
        for (int j = 0; j < 8; ++j) {
            int h = h0 + j;
            float v = (h < 441) ? src[h] * inv : 0.f;
            hs[j] = to_bf16(v);
        }
        uint4 H;
        H.x = hs[0] | (hs[1] << 16); H.y = hs[2] | (hs[3] << 16);
        H.z = hs[4] | (hs[5] << 16); H.w = hs[6] | (hs[7] << 16);
        Bl[idx] = H;
    } else {
        // cosine logits
        int e = bid - 3070;
        __shared__ float qp[30 * 64], pr[5 * 64], qn[30], pn[5];
        int t = tid;
        for (int li = t; li < 1920; li += 256) qp[li] = pool[e * 30 * 64 + li];
        for (int li = t; li < 320; li += 256) {
            int w = li >> 6, d = li & 63;
            float sm = 0.f;
            for (int sh = 0; sh < 5; ++sh) sm += pool[(60 + e * 25 + w * 5 + sh) * 64 + d];
            pr[li] = sm * 0.2f;
        }
        __syncthreads();
        if (t < 30) {
            float ss = 0.f;
            for (int d = 0; d < 64; ++d) { float v = qp[t * 64 + d]; ss = fmaf(v, v, ss); }
            qn[t] = 1.0f / sqrtf(ss);
        }
        if (t >= 32 && t < 37) {
            int w = t - 32; float ss = 0.f;
            for (int d = 0; d < 64; ++d) { float v = pr[w * 64 + d]; ss = fmaf(v, v, ss); }
            pn[w] = 1.0f / sqrtf(ss);
        }
        __syncthreads();
        if (t < 150) {
            int q = t / 5, w = t % 5;
            float dp = 0.f;
            for (int d = 0; d < 64; ++d) dp = fmaf(qp[q * 64 + d], pr[w * 64 + d], dp);
            feats[(e * 30 + q) * 15 + w] = dp * qn[q] * pn[w];
        }
    }
}

// ---------------- k6_pix: pixel similarity, modulo-3 named-bank pipeline ----
// grid = 8 XCDs x 263 slots; p = xcd*263+slot (2100 active); block = one
// gwave x 4 k-quarter waves (36/36/36/30 kt); cross-quarter merge via LDS.
#define PIXBODY(X0, X1, KIDX)                                              \
    do {                                                                   \
        _Pragma("unroll")                                                  \
        for (int s = 0; s < 4; ++s) {                                      \
            f32x4 cv = MFMA16(X0, Bh[s][0], ZV);                           \
            cv = MFMA16(X1, Bh[s][1], cv);                                 \
            _Pragma("unroll")                                              \
            for (int gg = 0; gg < 4; ++gg) ins5(m[s], cv[gg]);             \
        }                                                                  \
        X0 = As[(size_t)((KIDX) + 3) * 128];                               \
        X1 = As[(size_t)((KIDX) + 3) * 128 + 64];                          \
    } while (0)

#define PIXTAIL(X0, X1, KIDX)                                              \
    do {                                                                   \
        bool lastk = ((KIDX) == 137);                                      \
        _Pragma("unroll")                                                  \
        for (int s = 0; s < 4; ++s) {                                      \
            f32x4 cv = MFMA16(X0, Bh[s][0], ZV);                           \
            cv = MFMA16(X1, Bh[s][1], cv);                                 \
            _Pragma("unroll")                                              \
            for (int gg = 0; gg < 4; ++gg) {                               \
                float v = (lastk && (rowbase + gg >= 13)) ? -1e30f : cv[gg]; \
                ins5(m[s], v);                                             \
            }                                                              \
        }                                                                  \
    } while (0)

__attribute__((amdgpu_waves_per_eu(4, 4)))
__global__ __launch_bounds__(256) void k6_pix(const bf16x8* __restrict__ Pq,
                                              const bf16x8* __restrict__ Ps,
                                              float* __restrict__ part_p) {
    __shared__ float SH[1280];     // Msh[4][4][16][5]
    int bid = blockIdx.x;
    int tid = threadIdx.x;
    int xcd = bid & 7;
    int slot = bid >> 3;
    int wv = tid >> 6, lane = tid & 63;
    const f32x4 ZV = {0.f, 0.f, 0.f, 0.f};

    int p = xcd * 263 + slot;
    if (p >= 2100) return;
    int ew = p / 210;
    int gwave = p - ew * 210;
    int e = ew / 5, w = ew - (ew / 5) * 5;
    int q = gwave / 7;
    int ct0 = gwave * 4;
    int k0 = wv * 36;
    int kend = (wv == 3) ? 138 : k0 + 36;
    int T = (kend - k0 - 3) / 3;       // 11 or 9

    bf16x8 Bh[4][2];
#pragma unroll
    for (int s = 0; s < 4; ++s)
#pragma unroll
        for (int ks = 0; ks < 2; ++ks)
            Bh[s][ks] = Pq[((e * 840 + ct0 + s) * 2 + ks) * 64 + lane];

    float m[4][5];
#pragma unroll
    for (int s = 0; s < 4; ++s)
#pragma unroll
        for (int i = 0; i < 5; ++i) m[s][i] = -1e30f;

    int rowbase = (lane >> 4) * 4;
    const bf16x8* As = Ps + (size_t)(ew * 138) * 128 + lane;

    // prologue: 3 banks in flight
    bf16x8 a0 = As[(size_t)(k0 + 0) * 128], a1 = As[(size_t)(k0 + 0) * 128 + 64];
    bf16x8 b0 = As[(size_t)(k0 + 1) * 128], b1 = As[(size_t)(k0 + 1) * 128 + 64];
    bf16x8 c0 = As[(size_t)(k0 + 2) * 128], c1 = As[(size_t)(k0 + 2) * 128 + 64];

    int kt = k0;
    for (int i = 0; i < T; ++i) {
        PIXBODY(a0, a1, kt);
        PIXBODY(b0, b1, kt + 1);
        PIXBODY(c0, c1, kt + 2);
        kt += 3;
    }
    // epilogue: consume the 3 preloaded banks (kend-3..kend-1)
    PIXTAIL(a0, a1, kt);
    PIXTAIL(b0, b1, kt + 1);
    PIXTAIL(c0, c1, kt + 2);

    // merge per-set top5 across the 4 row-quad lane groups
#pragma unroll
    for (int mask = 16; mask <= 32; mask <<= 1) {
        float ov[4][5];
#pragma unroll
        for (int s = 0; s < 4; ++s)
#pragma unroll
            for (int i = 0; i < 5; ++i) ov[s][i] = __shfl_xor(m[s][i], mask, 64);
#pragma unroll
        for (int s = 0; s < 4; ++s)
#pragma unroll
            for (int i = 0; i < 5; ++i) ins5(m[s], ov[s][i]);
    }

    // cross-quarter merge via LDS
    float (*Msh)[4][16][5] = (float (*)[4][16][5])SH;
    if (lane < 16) {
#pragma unroll
        for (int s = 0; s < 4; ++s)
#pragma unroll
            for (int i = 0; i < 5; ++i) Msh[wv][s][lane][i] = m[s][i];
    }
    __syncthreads();
    if (wv == 0) {
        int s = lane >> 4, col = lane & 15;
        float lst[5];
#pragma unroll
        for (int i = 0; i < 5; ++i) lst[i] = Msh[0][s][col][i];
#pragma unroll
        for (int w2 = 1; w2 < 4; ++w2)
#pragma unroll
            for (int i = 0; i < 5; ++i) ins5(lst, Msh[w2][s][col][i]);
        float s5 = lst[0] + lst[1] + lst[2] + lst[3] + lst[4];
        int h = ((ct0 + s) % 28) * 16 + col;
        s5 = (h < 441) ? s5 : 0.f;
#pragma unroll
        for (int mask = 1; mask <= 32; mask <<= 1) s5 += __shfl_xor(s5, mask, 64);
        if (lane == 0) {
            int sl = gwave - q * 7;
            part_p[((e * 30 + q) * 5 + w) * 7 + sl] = s5;
        }
    }
}

// channel rr-pass: NRR row-tiles, full-K accumulate, then top5-insert.
template <int NRR>
__device__ __forceinline__ void chan_pass(int rr0, int ew, int e, int q, int wv, int lane,
                                          const bf16x8* __restrict__ Bl,
                                          const bf16x8* __restrict__ Al,
                                          float m[4][5]) {
    f32x4 cc[NRR][4];
#pragma unroll
    for (int r = 0; r < NRR; ++r)
#pragma unroll
        for (int s = 0; s < 4; ++s) cc[r][s] = (f32x4){0.f, 0.f, 0.f, 0.f};
    for (int ks = 0; ks < 14; ++ks) {
        bf16x8 bh[4];
#pragma unroll
        for (int s = 0; s < 4; ++s)
            bh[s] = Bl[((e * 120 + q * 4 + s) * 14 + ks) * 64 + lane];
#pragma unroll
        for (int r = 0; r < NRR; ++r) {
            bf16x8 ah = Al[((ew * 20 + wv * 5 + rr0 + r) * 14 + ks) * 64 + lane];
#pragma unroll
            for (int s = 0; s < 4; ++s) cc[r][s] = MFMA16(ah, bh[s], cc[r][s]);
        }
    }
#pragma unroll
    for (int r = 0; r < NRR; ++r)
#pragma unroll
        for (int s = 0; s < 4; ++s)
#pragma unroll
            for (int g = 0; g < 4; ++g) ins5(m[s], cc[r][s][g]);
}

// ---------------- k5_chan: channel similarity ----------------
__attribute__((amdgpu_waves_per_eu(4, 4)))
__global__ __launch_bounds__(256) void k5_chan(const bf16x8* __restrict__ Bl,
                                               const bf16x8* __restrict__ Al,
                                               float* __restrict__ siml) {
    __shared__ float Mred[4][64][5];
    int bid = blockIdx.x;
    int tid = threadIdx.x;
    int xcd = bid & 7;
    int slot = bid >> 3;
    int wv = tid >> 6, lane = tid & 63;

    int c = xcd * 38 + slot;
    if (c >= 300) return;
    int ew = c / 30, q = c - ew * 30;
    int e = ew / 5, w = ew - (ew / 5) * 5;

    float m[4][5];
#pragma unroll
    for (int s = 0; s < 4; ++s)
#pragma unroll
        for (int i = 0; i < 5; ++i) m[s][i] = -1e30f;

    chan_pass<3>(0, ew, e, q, wv, lane, Bl, Al, m);
    chan_pass<2>(3, ew, e, q, wv, lane, Bl, Al, m);

#pragma unroll
    for (int mask = 16; mask <= 32; mask <<= 1) {
        float ov[4][5];
#pragma unroll
        for (int s = 0; s < 4; ++s)
#pragma unroll
            for (int i = 0; i < 5; ++i) ov[s][i] = __shfl_xor(m[s][i], mask, 64);
#pragma unroll
        for (int s = 0; s < 4; ++s)
#pragma unroll
            for (int i = 0; i < 5; ++i) ins5(m[s], ov[s][i]);
    }

    if (lane < 16) {
#pragma unroll
        for (int s = 0; s < 4; ++s)
#pragma unroll
            for (int i = 0; i < 5; ++i) Mred[wv][s * 16 + lane][i] = m[s][i];
    }
    __syncthreads();

    if (tid < 64) {
        float lst[5];
#pragma unroll
        for (int i = 0; i < 5; ++i) lst[i] = Mred[0][tid][i];
#pragma unroll
        for (int v2 = 1; v2 < 4; ++v2)
#pragma unroll
            for (int i = 0; i < 5; ++i) ins5(lst, Mred[v2][tid][i]);
        float s5 = lst[0] + lst[1] + lst[2] + lst[3] + lst[4];
#pragma unroll
        for (int mask = 1; mask <= 32; mask <<= 1) s5 += __shfl_xor(s5, mask, 64);
        if (tid == 0) siml[(e * 30 + q) * 5 + w] = s5;
    }
}

// ---------------- k7: BN (episode stats) + dilated conv ----------------
__global__ __launch_bounds__(256) void k7_final(const float* __restrict__ feats,
                                                const float* __restrict__ siml,
                                                const float* __restrict__ part_p,
                                                const float* __restrict__ gamma,
                                                const float* __restrict__ beta,
                                                const float* __restrict__ convw,
                                                float* __restrict__ out) {
    int e = blockIdx.x;
    __shared__ float f[30 * 15], mu[15], inv[15];
    int t = threadIdx.x;
    if (t < 150) {
        int q = t / 5, w = t % 5;
        int pb = ((e * 30 + q) * 5 + w) * 7;
        float sp = 0.f;
#pragma unroll
        for (int s = 0; s < 7; ++s) sp += part_p[pb + s];
        f[q * 15 + w] = feats[(e * 30 + q) * 15 + w];
        f[q * 15 + 5 + w] = siml[(e * 30 + q) * 5 + w];
        f[q * 15 + 10 + w] = sp;
    }
    __syncthreads();
    if (t < 15) {
        float s1 = 0.f;
        for (int q = 0; q < 30; ++q) s1 += f[q * 15 + t];
        float mn = s1 * (1.0f / 30.0f);
        float s2 = 0.f;
        for (int q = 0; q < 30; ++q) { float d = f[q * 15 + t] - mn; s2 = fmaf(d, d, s2); }
        mu[t] = mn;
        inv[t] = 1.0f / sqrtf(s2 * (1.0f / 30.0f) + 1e-5f);
    }
    __syncthreads();
    if (t < 150) {
        int q = t / 5, j = t % 5;
        float w0 = convw[0], w1 = convw[1], w2 = convw[2];
        float b0 = (f[q * 15 + j]      - mu[j])      * inv[j]      * gamma[j]      + beta[j];
        float b1 = (f[q * 15 + 5 + j]  - mu[5 + j])  * inv[5 + j]  * gamma[5 + j]  + beta[5 + j];
        float b2 = (f[q * 15 + 10 + j] - mu[10 + j]) * inv[10 + j] * gamma[10 + j] + beta[10 + j];
        out[e * 150 + q * 5 + j] = w0 * b0 + w1 * b1 + w2 * b2;
    }
}

extern "C" void kernel_launch(void* const* d_in, const int* in_sizes, int n_in,
                              void* d_out, int out_size, void* d_ws, size_t ws_size,
                              hipStream_t stream) {
    const float* in1 = (const float*)d_in[0];
    const float* in2 = (const float*)d_in[1];
    const float* gamma = (const float*)d_in[2];
    const float* beta = (const float*)d_in[3];
    const float* convw = (const float*)d_in[4];
    float* out = (float*)d_out;

    char* ws = (char*)d_ws;
    float* inv_norm = (float*)(ws + 0);                    //  28,160 B
    float* pool     = (float*)(ws + 28160);                //  28,160 B
    float* feats    = (float*)(ws + 56320);                //   3,600 B
    float* siml     = (float*)(ws + 59920);                //   1,200 B
    float* part_p   = (float*)(ws + 61120);                //   8,400 B
    size_t o = 69520;
    uint4* Pq = (uint4*)(ws + o); o += 3440640;
    uint4* Ps = (uint4*)(ws + o); o += 2826240;
    uint4* Al = (uint4*)(ws + o); o += 2867200;
    uint4* Bl = (uint4*)(ws + o); o += 3440640;   // total ~12.7 MB

    k1_rownorm<<<dim3(1760), dim3(256), 0, stream>>>(in1, in2, inv_norm, pool);
    pack_all<<<dim3(3072), dim3(256), 0, stream>>>(in1, in2, inv_norm, pool,
                                                   Pq, Ps, Al, Bl, feats);
    k6_pix<<<dim3(2104), dim3(256), 0, stream>>>((const bf16x8*)Pq, (const bf16x8*)Ps,
                                                 part_p);
    k5_chan<<<dim3(304), dim3(256), 0, stream>>>((const bf16x8*)Bl, (const bf16x8*)Al,
                                                 siml);
    k7_final<<<dim3(2), dim3(256), 0, stream>>>(feats, siml, part_p, gamma, beta, convw, out);
}